// Round 1
// baseline (1035.676 us; speedup 1.0000x reference)
//
#include <hip/hip_runtime.h>

// ---------------- graph preprocessing ----------------

__global__ void k_count(const int* __restrict__ ei, int E,
                        int* __restrict__ deg_src, int* __restrict__ cnt_dst) {
  int i = blockIdx.x * blockDim.x + threadIdx.x;
  if (i >= E) return;
  int dst = ei[i];        // edge_index[0] = row = destination
  int src = ei[E + i];    // edge_index[1] = col = source
  atomicAdd(&deg_src[src], 1);
  atomicAdd(&cnt_dst[dst], 1);
}

__global__ void k_dis(const int* __restrict__ deg_src, float* __restrict__ dis, int N) {
  int i = blockIdx.x * blockDim.x + threadIdx.x;
  if (i >= N) return;
  // degree = out-occurrences as source + 1 (self-loop); always >= 1
  dis[i] = rsqrtf((float)(deg_src[i] + 1));
}

// 3-phase exclusive scan over cnt_dst -> offsets
__global__ void k_scan1(const int* __restrict__ cnt, int* __restrict__ offs,
                        int* __restrict__ partial, int N) {
  __shared__ int s[1024];
  int t = threadIdx.x;
  int i = blockIdx.x * 1024 + t;
  int v = (i < N) ? cnt[i] : 0;
  s[t] = v;
  __syncthreads();
  for (int off = 1; off < 1024; off <<= 1) {
    int x = (t >= off) ? s[t - off] : 0;
    __syncthreads();
    s[t] += x;
    __syncthreads();
  }
  if (i < N) offs[i] = s[t] - v;              // exclusive
  if (t == 1023) partial[blockIdx.x] = s[1023]; // block total
}

__global__ void k_scan2(int* __restrict__ partial, int nb) {
  if (blockIdx.x == 0 && threadIdx.x == 0) {
    int run = 0;
    for (int j = 0; j < nb; ++j) { int tv = partial[j]; partial[j] = run; run += tv; }
  }
}

__global__ void k_scan3(int* __restrict__ offs, const int* __restrict__ partial,
                        int* __restrict__ cursor, int N, int E) {
  int t = threadIdx.x;
  int i = blockIdx.x * 1024 + t;
  if (i < N) {
    int o = offs[i] + partial[blockIdx.x];
    offs[i] = o;
    cursor[i] = o;
  }
  if (i == 0) offs[N] = E;
}

__global__ void k_sort(const int* __restrict__ ei, int E,
                       int* __restrict__ cursor, int* __restrict__ srcs) {
  int i = blockIdx.x * blockDim.x + threadIdx.x;
  if (i >= E) return;
  int dst = ei[i];
  int src = ei[E + i];
  int p = atomicAdd(&cursor[dst], 1);
  srcs[p] = src;
}

// ---------------- fp32 GEMM: hw[r][c] = act(in[r][:]) @ W[:, c] ----------------
// 128x128 block tile; W (64KB) + h^T (64KB) in LDS; 256 thr = 4 waves, each wave
// owns a 64x64 quadrant, lane grid 8x8, 8x8 fp32 acc per thread.

__global__ __launch_bounds__(256, 1)
void k_gemm(const float* __restrict__ in, int in_stride, int do_relu,
            const float* __restrict__ W, float* __restrict__ hw, int N) {
  __shared__ float hT[128 * 128];
  __shared__ float Wl[128 * 128];
  int t = threadIdx.x;
  int rbase = blockIdx.x * 128;

  // stage W (row-major, linear copy)
#pragma unroll
  for (int i = 0; i < 16; ++i) {
    int s4 = t + i * 256;
    ((float4*)Wl)[s4] = ((const float4*)W)[s4];
  }
  // stage h transposed: hT[k][r]
#pragma unroll
  for (int i = 0; i < 16; ++i) {
    int s4 = t + i * 256;          // float4 slot
    int r = s4 & 127, kb = s4 >> 7;
    float4 v = make_float4(0.f, 0.f, 0.f, 0.f);
    int gr = rbase + r;
    if (gr < N) {
      v = *(const float4*)(in + (size_t)gr * in_stride + kb * 4);
      if (do_relu) {
        v.x = fmaxf(v.x, 0.f); v.y = fmaxf(v.y, 0.f);
        v.z = fmaxf(v.z, 0.f); v.w = fmaxf(v.w, 0.f);
      }
    }
    int kk = kb * 4;
    hT[(kk + 0) * 128 + r] = v.x;
    hT[(kk + 1) * 128 + r] = v.y;
    hT[(kk + 2) * 128 + r] = v.z;
    hT[(kk + 3) * 128 + r] = v.w;
  }
  __syncthreads();

  int wv = t >> 6, lane = t & 63;
  int r0 = (wv >> 1) * 64 + (lane >> 3) * 8;
  int c0 = (wv & 1) * 64 + (lane & 7) * 8;

  float acc[8][8];
#pragma unroll
  for (int i = 0; i < 8; ++i)
#pragma unroll
    for (int j = 0; j < 8; ++j) acc[i][j] = 0.f;

#pragma unroll 2
  for (int k = 0; k < 128; ++k) {
    float4 a0 = *(const float4*)&hT[k * 128 + r0];
    float4 a1 = *(const float4*)&hT[k * 128 + r0 + 4];
    float4 b0 = *(const float4*)&Wl[k * 128 + c0];
    float4 b1 = *(const float4*)&Wl[k * 128 + c0 + 4];
    float a[8] = {a0.x, a0.y, a0.z, a0.w, a1.x, a1.y, a1.z, a1.w};
    float b[8] = {b0.x, b0.y, b0.z, b0.w, b1.x, b1.y, b1.z, b1.w};
#pragma unroll
    for (int i = 0; i < 8; ++i)
#pragma unroll
      for (int j = 0; j < 8; ++j)
        acc[i][j] = fmaf(a[i], b[j], acc[i][j]);
  }

#pragma unroll
  for (int i = 0; i < 8; ++i) {
    int gr = rbase + r0 + i;
    if (gr < N) {
      float4 o0 = make_float4(acc[i][0], acc[i][1], acc[i][2], acc[i][3]);
      float4 o1 = make_float4(acc[i][4], acc[i][5], acc[i][6], acc[i][7]);
      *(float4*)(hw + (size_t)gr * 128 + c0) = o0;
      *(float4*)(hw + (size_t)gr * 128 + c0 + 4) = o1;
    }
  }
}

// ---------------- aggregation: one wave per node, atomic-free ----------------

__global__ __launch_bounds__(256)
void k_agg(const float* __restrict__ hw, const int* __restrict__ offs,
           const int* __restrict__ srcs, const float* __restrict__ dis,
           const float* __restrict__ bias, float* __restrict__ out,
           int N, int layer) {
  int wv = threadIdx.x >> 6;
  int lane = threadIdx.x & 63;
  int v = blockIdx.x * 4 + wv;
  if (v >= N) return;

  float dv = dis[v];
  const float2* hw2 = (const float2*)hw;
  float2 h = hw2[(size_t)v * 64 + lane];
  float sn = dv * dv;                 // self-loop norm
  float ax = sn * h.x, ay = sn * h.y;

  int e0 = offs[v], e1 = offs[v + 1];
  for (int e = e0; e < e1; ++e) {
    int s = srcs[e];
    float w = dv * dis[s];
    float2 hs = hw2[(size_t)s * 64 + lane];
    ax = fmaf(w, hs.x, ax);
    ay = fmaf(w, hs.y, ay);
  }
  float2 b = ((const float2*)bias)[lane];
  float2 o = make_float2(ax + b.x, ay + b.y);
  *(float2*)(out + (size_t)v * 384 + layer * 128 + 2 * lane) = o;
}

// ---------------- launch ----------------

extern "C" void kernel_launch(void* const* d_in, const int* in_sizes, int n_in,
                              void* d_out, int out_size, void* d_ws, size_t ws_size,
                              hipStream_t stream) {
  const float* x  = (const float*)d_in[0];
  const int*   ei = (const int*)d_in[1];
  const float* W0 = (const float*)d_in[2];
  const float* b0 = (const float*)d_in[3];
  const float* W1 = (const float*)d_in[4];
  const float* b1 = (const float*)d_in[5];
  const float* W2 = (const float*)d_in[6];
  const float* b2 = (const float*)d_in[7];
  float* out = (float*)d_out;

  int N = in_sizes[0] / 128;
  int E = in_sizes[1] / 2;

  char* p = (char*)d_ws;
  auto alloc = [&](size_t sz) { char* r = p; p += (sz + 255) & ~(size_t)255; return r; };
  float* hw      = (float*)alloc((size_t)N * 128 * 4);
  float* dis     = (float*)alloc((size_t)N * 4);
  int*   deg     = (int*)alloc((size_t)N * 4);
  int*   cnt     = (int*)alloc((size_t)N * 4);
  int*   offs    = (int*)alloc((size_t)(N + 1) * 4);
  int*   cursor  = (int*)alloc((size_t)N * 4);
  int*   srcs    = (int*)alloc((size_t)E * 4);
  int*   partial = (int*)alloc(1024 * 4);

  hipMemsetAsync(deg, 0, (size_t)N * 4, stream);
  hipMemsetAsync(cnt, 0, (size_t)N * 4, stream);

  int gE = (E + 255) / 256;
  int nch = (N + 1023) / 1024;
  k_count<<<gE, 256, 0, stream>>>(ei, E, deg, cnt);
  k_dis<<<(N + 255) / 256, 256, 0, stream>>>(deg, dis, N);
  k_scan1<<<nch, 1024, 0, stream>>>(cnt, offs, partial, N);
  k_scan2<<<1, 64, 0, stream>>>(partial, nch);
  k_scan3<<<nch, 1024, 0, stream>>>(offs, partial, cursor, N, E);
  k_sort<<<gE, 256, 0, stream>>>(ei, E, cursor, srcs);

  int gG = (N + 127) / 128;
  int gA = (N + 3) / 4;

  // layer 0
  k_gemm<<<gG, 256, 0, stream>>>(x, 128, 0, W0, hw, N);
  k_agg<<<gA, 256, 0, stream>>>(hw, offs, srcs, dis, b0, out, N, 0);
  // layer 1: input = relu(out[:,0,:]) (stride 384)
  k_gemm<<<gG, 256, 0, stream>>>(out, 384, 1, W1, hw, N);
  k_agg<<<gA, 256, 0, stream>>>(hw, offs, srcs, dis, b1, out, N, 1);
  // layer 2: input = relu(out[:,1,:])
  k_gemm<<<gG, 256, 0, stream>>>(out + 128, 384, 1, W2, hw, N);
  k_agg<<<gA, 256, 0, stream>>>(hw, offs, srcs, dis, b2, out, N, 2);
}

// Round 2
// 578.226 us; speedup vs baseline: 1.7911x; 1.7911x over previous
//
#include <hip/hip_runtime.h>

typedef _Float16 half8 __attribute__((ext_vector_type(8)));
typedef _Float16 half4 __attribute__((ext_vector_type(4)));
typedef _Float16 half2v __attribute__((ext_vector_type(2)));
typedef float f4 __attribute__((ext_vector_type(4)));

// ---------------- graph preprocessing ----------------

__global__ void k_count(const int* __restrict__ ei, int E,
                        int* __restrict__ deg_src, int* __restrict__ cnt_dst) {
  int i = blockIdx.x * blockDim.x + threadIdx.x;
  if (i >= E) return;
  int dst = ei[i];        // edge_index[0] = row = destination
  int src = ei[E + i];    // edge_index[1] = col = source
  atomicAdd(&deg_src[src], 1);
  atomicAdd(&cnt_dst[dst], 1);
}

__global__ void k_dis(const int* __restrict__ deg_src, float* __restrict__ dis, int N) {
  int i = blockIdx.x * blockDim.x + threadIdx.x;
  if (i >= N) return;
  dis[i] = rsqrtf((float)(deg_src[i] + 1));
}

__global__ void k_scan1(const int* __restrict__ cnt, int* __restrict__ offs,
                        int* __restrict__ partial, int N) {
  __shared__ int s[1024];
  int t = threadIdx.x;
  int i = blockIdx.x * 1024 + t;
  int v = (i < N) ? cnt[i] : 0;
  s[t] = v;
  __syncthreads();
  for (int off = 1; off < 1024; off <<= 1) {
    int x = (t >= off) ? s[t - off] : 0;
    __syncthreads();
    s[t] += x;
    __syncthreads();
  }
  if (i < N) offs[i] = s[t] - v;
  if (t == 1023) partial[blockIdx.x] = s[1023];
}

__global__ void k_scan2(int* __restrict__ partial, int nb) {
  if (blockIdx.x == 0 && threadIdx.x == 0) {
    int run = 0;
    for (int j = 0; j < nb; ++j) { int tv = partial[j]; partial[j] = run; run += tv; }
  }
}

__global__ void k_scan3(int* __restrict__ offs, const int* __restrict__ partial,
                        int* __restrict__ cursor, int N, int E) {
  int t = threadIdx.x;
  int i = blockIdx.x * 1024 + t;
  if (i < N) {
    int o = offs[i] + partial[blockIdx.x];
    offs[i] = o;
    cursor[i] = o;
  }
  if (i == 0) offs[N] = E;
}

__global__ void k_sort(const int* __restrict__ ei, int E,
                       int* __restrict__ cursor, int* __restrict__ srcs) {
  int i = blockIdx.x * blockDim.x + threadIdx.x;
  if (i >= E) return;
  int dst = ei[i];
  int src = ei[E + i];
  int p = atomicAdd(&cursor[dst], 1);
  srcs[p] = src;
}

// W (128x128 fp32 row-major, W[k][c]) -> Wt fp16 transposed: Wt[c][k]
__global__ void k_prepw(const float* __restrict__ W0, const float* __restrict__ W1,
                        const float* __restrict__ W2, _Float16* __restrict__ Wt) {
  int i = blockIdx.x * blockDim.x + threadIdx.x;   // 0..49151
  int m = i >> 14;
  int j = i & 16383;
  int c = j >> 7, k = j & 127;
  const float* W = (m == 0) ? W0 : (m == 1) ? W1 : W2;
  Wt[i] = (_Float16)W[k * 128 + c];
}

// ---------------- fp16 MFMA GEMM + dis-scale epilogue ----------------
// hws[r][:] = dis[r] * (relu?(in[r][:]) @ W)  as fp16.
// Swapped operands: A = W^T (M-dim = W cols), B = h^T (N-dim = h rows).
// Block: 256 thr = 4 waves, 128 rows/block (32 rows/wave = 2 m-frags), 128 cols.

#define LDH 136   // padded halves per row (272 B) -> conflict-free ds_read_b128

__global__ __launch_bounds__(256, 2)
void k_gemm(const float* __restrict__ in, int in_stride, int do_relu,
            const _Float16* __restrict__ Wt_g, const float* __restrict__ dis,
            _Float16* __restrict__ hws, int N) {
  __shared__ _Float16 Wt[128 * LDH];
  int t = threadIdx.x;
  int rbase = blockIdx.x * 128;

  // stage Wt: 16384 halves = 2048 16B-chunks; coalesced global, padded LDS
#pragma unroll
  for (int i = 0; i < 8; ++i) {
    int s = t + i * 256;
    int c = s >> 4, kh = s & 15;
    half8 w = ((const half8*)Wt_g)[s];
    *(half8*)&Wt[c * LDH + kh * 8] = w;
  }
  __syncthreads();

  int wv = t >> 6, lane = t & 63;
  int r0 = wv * 32;
  int lr = lane & 15, lg = lane >> 4;   // lg = k-group (0..3)

  f4 acc[2][8];
#pragma unroll
  for (int fm = 0; fm < 2; ++fm)
#pragma unroll
    for (int fn = 0; fn < 8; ++fn) acc[fm][fn] = (f4){0.f, 0.f, 0.f, 0.f};

#pragma unroll
  for (int ks = 0; ks < 4; ++ks) {
    int k0 = ks * 32 + lg * 8;
    // A frags (W^T): lane = W-col (lr), 8 contiguous k
    half8 a[8];
#pragma unroll
    for (int fn = 0; fn < 8; ++fn)
      a[fn] = *(const half8*)&Wt[(fn * 16 + lr) * LDH + k0];
#pragma unroll
    for (int fm = 0; fm < 2; ++fm) {
      int gr = rbase + r0 + fm * 16 + lr;
      float4 v0 = make_float4(0.f, 0.f, 0.f, 0.f);
      float4 v1 = make_float4(0.f, 0.f, 0.f, 0.f);
      if (gr < N) {
        const float* pr = in + (size_t)gr * in_stride + k0;
        v0 = *(const float4*)pr;
        v1 = *(const float4*)(pr + 4);
      }
      if (do_relu) {
        v0.x = fmaxf(v0.x, 0.f); v0.y = fmaxf(v0.y, 0.f);
        v0.z = fmaxf(v0.z, 0.f); v0.w = fmaxf(v0.w, 0.f);
        v1.x = fmaxf(v1.x, 0.f); v1.y = fmaxf(v1.y, 0.f);
        v1.z = fmaxf(v1.z, 0.f); v1.w = fmaxf(v1.w, 0.f);
      }
      half8 b;
      b[0] = (_Float16)v0.x; b[1] = (_Float16)v0.y;
      b[2] = (_Float16)v0.z; b[3] = (_Float16)v0.w;
      b[4] = (_Float16)v1.x; b[5] = (_Float16)v1.y;
      b[6] = (_Float16)v1.z; b[7] = (_Float16)v1.w;
#pragma unroll
      for (int fn = 0; fn < 8; ++fn)
        acc[fm][fn] = __builtin_amdgcn_mfma_f32_16x16x32_f16(a[fn], b, acc[fm][fn], 0, 0, 0);
    }
  }

  // epilogue: D frag: lane holds out-row (lr-based), 4 consecutive cols at 4*lg
#pragma unroll
  for (int fm = 0; fm < 2; ++fm) {
    int gr = rbase + r0 + fm * 16 + lr;
    if (gr >= N) continue;
    float dv = dis[gr];
#pragma unroll
    for (int fn = 0; fn < 8; ++fn) {
      f4 d = acc[fm][fn];
      half4 hv;
      hv[0] = (_Float16)(d[0] * dv);
      hv[1] = (_Float16)(d[1] * dv);
      hv[2] = (_Float16)(d[2] * dv);
      hv[3] = (_Float16)(d[3] * dv);
      *(half4*)(hws + (size_t)gr * 128 + fn * 16 + lg * 4) = hv;
    }
  }
}

// ---------------- aggregation: wave/node, fp16 gathers, 8-deep MLP ----------------

__global__ __launch_bounds__(256)
void k_agg(const _Float16* __restrict__ hws, const int* __restrict__ offs,
           const int* __restrict__ srcs, const float* __restrict__ dis,
           const float* __restrict__ bias, float* __restrict__ out,
           int N, int layer) {
  int wv = threadIdx.x >> 6, lane = threadIdx.x & 63;
  int v = blockIdx.x * 4 + wv;
  if (v >= N) return;

  const uint* h32 = (const uint*)hws;   // one dword = 2 fp16 features per lane
  uint hv = h32[(size_t)v * 64 + lane]; // self term (hws already scaled by dis)
  half2v h = __builtin_bit_cast(half2v, hv);
  float ax = (float)h[0], ay = (float)h[1];

  int e0 = offs[v], e1 = offs[v + 1];
  int e = e0;
  for (; e + 8 <= e1; e += 8) {
    int s0 = srcs[e + 0], s1 = srcs[e + 1], s2 = srcs[e + 2], s3 = srcs[e + 3];
    int s4 = srcs[e + 4], s5 = srcs[e + 5], s6 = srcs[e + 6], s7 = srcs[e + 7];
    uint u0 = h32[(size_t)s0 * 64 + lane];
    uint u1 = h32[(size_t)s1 * 64 + lane];
    uint u2 = h32[(size_t)s2 * 64 + lane];
    uint u3 = h32[(size_t)s3 * 64 + lane];
    uint u4 = h32[(size_t)s4 * 64 + lane];
    uint u5 = h32[(size_t)s5 * 64 + lane];
    uint u6 = h32[(size_t)s6 * 64 + lane];
    uint u7 = h32[(size_t)s7 * 64 + lane];
    half2v p0 = __builtin_bit_cast(half2v, u0);
    half2v p1 = __builtin_bit_cast(half2v, u1);
    half2v p2 = __builtin_bit_cast(half2v, u2);
    half2v p3 = __builtin_bit_cast(half2v, u3);
    half2v p4 = __builtin_bit_cast(half2v, u4);
    half2v p5 = __builtin_bit_cast(half2v, u5);
    half2v p6 = __builtin_bit_cast(half2v, u6);
    half2v p7 = __builtin_bit_cast(half2v, u7);
    ax += (float)p0[0] + (float)p1[0] + (float)p2[0] + (float)p3[0]
        + (float)p4[0] + (float)p5[0] + (float)p6[0] + (float)p7[0];
    ay += (float)p0[1] + (float)p1[1] + (float)p2[1] + (float)p3[1]
        + (float)p4[1] + (float)p5[1] + (float)p6[1] + (float)p7[1];
  }
  for (; e < e1; ++e) {
    int s = srcs[e];
    uint u = h32[(size_t)s * 64 + lane];
    half2v p = __builtin_bit_cast(half2v, u);
    ax += (float)p[0];
    ay += (float)p[1];
  }

  float dv = dis[v];
  float2 b = ((const float2*)bias)[lane];
  float2 o;
  o.x = fmaf(dv, ax, b.x);
  o.y = fmaf(dv, ay, b.y);
  *(float2*)(out + (size_t)v * 384 + layer * 128 + 2 * lane) = o;
}

// ---------------- launch ----------------

extern "C" void kernel_launch(void* const* d_in, const int* in_sizes, int n_in,
                              void* d_out, int out_size, void* d_ws, size_t ws_size,
                              hipStream_t stream) {
  const float* x  = (const float*)d_in[0];
  const int*   ei = (const int*)d_in[1];
  const float* W0 = (const float*)d_in[2];
  const float* b0 = (const float*)d_in[3];
  const float* W1 = (const float*)d_in[4];
  const float* b1 = (const float*)d_in[5];
  const float* W2 = (const float*)d_in[6];
  const float* b2 = (const float*)d_in[7];
  float* out = (float*)d_out;

  int N = in_sizes[0] / 128;
  int E = in_sizes[1] / 2;

  char* p = (char*)d_ws;
  auto alloc = [&](size_t sz) { char* r = p; p += (sz + 255) & ~(size_t)255; return r; };
  _Float16* hws  = (_Float16*)alloc((size_t)N * 128 * 2);
  float* dis     = (float*)alloc((size_t)N * 4);
  int*   deg     = (int*)alloc((size_t)N * 4);
  int*   cnt     = (int*)alloc((size_t)N * 4);
  int*   offs    = (int*)alloc((size_t)(N + 1) * 4);
  int*   cursor  = (int*)alloc((size_t)N * 4);
  int*   srcs    = (int*)alloc((size_t)E * 4);
  int*   partial = (int*)alloc(1024 * 4);
  _Float16* Wt   = (_Float16*)alloc((size_t)3 * 128 * 128 * 2);

  hipMemsetAsync(deg, 0, (size_t)N * 4, stream);
  hipMemsetAsync(cnt, 0, (size_t)N * 4, stream);

  int gE = (E + 255) / 256;
  int nch = (N + 1023) / 1024;
  k_count<<<gE, 256, 0, stream>>>(ei, E, deg, cnt);
  k_dis<<<(N + 255) / 256, 256, 0, stream>>>(deg, dis, N);
  k_scan1<<<nch, 1024, 0, stream>>>(cnt, offs, partial, N);
  k_scan2<<<1, 64, 0, stream>>>(partial, nch);
  k_scan3<<<nch, 1024, 0, stream>>>(offs, partial, cursor, N, E);
  k_sort<<<gE, 256, 0, stream>>>(ei, E, cursor, srcs);
  k_prepw<<<192, 256, 0, stream>>>(W0, W1, W2, Wt);

  int gG = (N + 127) / 128;
  int gA = (N + 3) / 4;

  // layer 0
  k_gemm<<<gG, 256, 0, stream>>>(x, 128, 0, Wt, dis, hws, N);
  k_agg<<<gA, 256, 0, stream>>>(hws, offs, srcs, dis, b0, out, N, 0);
  // layer 1: input = relu(out[:,0,:]) (stride 384)
  k_gemm<<<gG, 256, 0, stream>>>(out, 384, 1, Wt + 16384, dis, hws, N);
  k_agg<<<gA, 256, 0, stream>>>(hws, offs, srcs, dis, b1, out, N, 1);
  // layer 2: input = relu(out[:,1,:])
  k_gemm<<<gG, 256, 0, stream>>>(out + 128, 384, 1, Wt + 32768, dis, hws, N);
  k_agg<<<gA, 256, 0, stream>>>(hws, offs, srcs, dis, b2, out, N, 2);
}